// Round 2
// baseline (613.550 us; speedup 1.0000x reference)
//
#include <hip/hip_runtime.h>
#include <cstdint>
#include <cstddef>

typedef __bf16 bf16x8 __attribute__((ext_vector_type(8)));
typedef float f32x4 __attribute__((ext_vector_type(4)));
typedef unsigned short u16;
typedef u16 u16x4 __attribute__((ext_vector_type(4)));
typedef u16 u16x8 __attribute__((ext_vector_type(8)));

// fp32 -> bf16 round-to-nearest-even
__device__ __forceinline__ u16 f2bf(float f) {
  union { float f; unsigned u; } v; v.f = f;
  return (u16)((v.u + 0x7FFFu + ((v.u >> 16) & 1u)) >> 16);
}

// ---------------------------------------------------------------------------
// Pre-pass: fp32 -> bf16 + MFMA *fragment-major* layout, SOURCE-indexed.
// If sel != null: block converts source plane z only if z appears in sel[0..31]
// (route dedup: level-3 tree route has only 8 distinct experts -> 4x less work).
// out[(((s*NB + nb)*KT + kt)*64 + l)*8 + e] = in[s][kt*32 + (l>>4)*8 + e][nb*16 + (l&15)]
// ---------------------------------------------------------------------------
__global__ void frag_cvt(const float* __restrict__ in, const int* __restrict__ sel,
                         u16* __restrict__ out, int K, int N) {
  const int s = blockIdx.z;
  if (sel) {
    bool need = false;
#pragma unroll
    for (int i = 0; i < 32; ++i) need |= (sel[i] == s);
    if (!need) return;
  }
  const int f = threadIdx.x >> 6, l = threadIdx.x & 63;
  const int r = l & 15, q = l >> 4;
  const int kt = blockIdx.x * 4 + f;
  const int nb = blockIdx.y;
  const int KT = K >> 5, NB = N >> 4;
  const float* ip = in + (size_t)s * K * N + (size_t)(kt * 32 + q * 8) * N + nb * 16 + r;
  u16x8 d;
#pragma unroll
  for (int e = 0; e < 8; ++e) d[e] = f2bf(ip[(size_t)e * N]);
  *(u16x8*)&out[((((size_t)s * NB + nb) * KT + kt) * 64 + l) * 8] = d;
}

// ---------------------------------------------------------------------------
// 64-row x 64-col x 512-k GEMM slice per wave.
// A: frag-major LDS, wave-uniform base + l*16 per fragment (conflict-free).
//    Af points at (wm-half, lane) base; kt stride 4096 u16, mt stride 512 u16.
// B: frag-major global (L2/L1-resident), 1-deep register prefetch.
// ---------------------------------------------------------------------------
__device__ __forceinline__ void gemm64(const u16* __restrict__ Bw, const u16* __restrict__ Af,
                                       f32x4 acc[4][4]) {
  bf16x8 bcur[4], bnxt[4];
#pragma unroll
  for (int nt = 0; nt < 4; ++nt) bcur[nt] = *(const bf16x8*)(Bw + nt * 8192);
#pragma unroll
  for (int kt = 0; kt < 16; ++kt) {
    if (kt < 15) {
#pragma unroll
      for (int nt = 0; nt < 4; ++nt)
        bnxt[nt] = *(const bf16x8*)(Bw + nt * 8192 + (kt + 1) * 512);
    }
#pragma unroll
    for (int mt = 0; mt < 4; ++mt) {
      const bf16x8 af = *(const bf16x8*)(Af + kt * 4096 + mt * 512);
#pragma unroll
      for (int nt = 0; nt < 4; ++nt)   // swapped operands => lane holds m=r, n=q*4+reg
        acc[mt][nt] = __builtin_amdgcn_mfma_f32_16x16x32_bf16(bcur[nt], af, acc[mt][nt], 0, 0, 0);
    }
#pragma unroll
    for (int nt = 0; nt < 4; ++nt) bcur[nt] = bnxt[nt];
  }
}

// relu + bias epilogue -> frag-major Xs.
// lane (r,q) acc[mt][nt] holds X[(wm*4+mt)*16+r][wn*64+nt*16+q*4 + j], j=0..3
// frag coords: kt2 = col>>5, q2 = (col>>3)&3, elem = (q&1)*4 + j
__device__ __forceinline__ void epi_relu(u16* __restrict__ Xs, const float* __restrict__ bias,
                                         f32x4 acc[4][4], int wm, int wn, int r, int q) {
#pragma unroll
  for (int mt = 0; mt < 4; ++mt) {
    const int MT = wm * 4 + mt;
#pragma unroll
    for (int nt = 0; nt < 4; ++nt) {
      const int col = wn * 64 + nt * 16 + q * 4;
      const int kt2 = col >> 5;
      const int q2 = (col >> 3) & 3;
      const float4 bb = *(const float4*)&bias[col];
      const f32x4 v = acc[mt][nt];
      const u16x4 d = { f2bf(fmaxf(v.x + bb.x, 0.f)), f2bf(fmaxf(v.y + bb.y, 0.f)),
                        f2bf(fmaxf(v.z + bb.z, 0.f)), f2bf(fmaxf(v.w + bb.w, 0.f)) };
      *(u16x4*)&Xs[((kt2 * 8 + MT) * 64 + q2 * 16 + r) * 8 + (q & 1) * 4] = d;
    }
  }
}

// ---------------------------------------------------------------------------
// Fused 3-layer MLP per (128-row batch tile, agent). 1024 threads / 16 waves.
// Xs: 128 KB frag-major [kt 16][MT 8][lane 64][8] bf16 (x0 -> X1 -> h in place).
// Wave (wm = w>>3, wn = w&7): rows wm*64..+63, cols wn*64..+63.
// Wave pairs (0,wn)/(1,wn) read identical B fragments -> L1 twin reuse;
// L2 B-traffic halved vs M=64. No k-loop barriers (5 barriers total).
// ---------------------------------------------------------------------------
__global__ __launch_bounds__(1024, 4)
void fused_mlp(const float* __restrict__ X0, const u16* __restrict__ Wsf,
               const float* __restrict__ bsh, const u16* __restrict__ W1f,
               const float* __restrict__ b1, const u16* __restrict__ W2f,
               const float* __restrict__ b2, const int* __restrict__ route,
               float* __restrict__ Out) {
  __shared__ u16 Xs[65536];                  // 128 KB

  const int tid = threadIdx.x;
  const int w = tid >> 6, l = tid & 63;
  const int r = l & 15, q = l >> 4;
  const int wm = w >> 3, wn = w & 7;

  // XCD-pinned: agent a on xcd = a>>2 (distinct experts <= 2 MB per L2)
  const int bid = blockIdx.x;                // 1024 blocks, 1024 % 8 == 0
  const int xcd = bid & 7, idx = bid >> 3;   // idx 0..127 per xcd
  const int a = (xcd << 2) | (idx >> 5);
  const int b0 = (idx & 31) << 7;            // 128-row tile
  const int rt = route[a];

  // ========== phase 0: x0 -> Xs frag-major ==========
  // thread (w,l): row m = (w&7)*16 + r (MTg = w&7), granules g = (w>>3)*32 + i*4 + q
  // -> per wave-iter: one full fragment, LDS write = uniform base + l*16 (conflict-free),
  //    global = 16 rows x 128 B contiguous.
  {
    const int m = ((w & 7) << 4) + r;
    const float* p = X0 + ((size_t)b0 * 32 + a) * 512 + (size_t)m * 16384
                   + ((w >> 3) << 8) + (q << 3);
    const int ktb = (w >> 3) << 3;           // 0 or 8
#pragma unroll
    for (int i = 0; i < 8; ++i) {
      const float4 u = *(const float4*)(p + i * 32);
      const float4 v = *(const float4*)(p + i * 32 + 4);
      const u16x8 d = { f2bf(u.x), f2bf(u.y), f2bf(u.z), f2bf(u.w),
                        f2bf(v.x), f2bf(v.y), f2bf(v.z), f2bf(v.w) };
      *(u16x8*)&Xs[((ktb + i) * 8 + (w & 7)) * 512 + l * 8] = d;
    }
  }
  __syncthreads();

  f32x4 acc[4][4];
  const u16* Af = Xs + (wm << 11) + l * 8;   // wm-half base

  // ========== phase 1: X1 = relu(x0 @ Ws + bs) ==========
#pragma unroll
  for (int mt = 0; mt < 4; ++mt)
#pragma unroll
    for (int nt = 0; nt < 4; ++nt) acc[mt][nt] = (f32x4){0.f, 0.f, 0.f, 0.f};
  gemm64(Wsf + (wn << 15) + l * 8, Af, acc);
  __syncthreads();                           // all x0 reads done
  epi_relu(Xs, bsh, acc, wm, wn, r, q);
  __syncthreads();                           // X1 visible

  // ========== phase 2: h = relu(X1 @ W1[rt]^T + b1[rt]) ==========
#pragma unroll
  for (int mt = 0; mt < 4; ++mt)
#pragma unroll
    for (int nt = 0; nt < 4; ++nt) acc[mt][nt] = (f32x4){0.f, 0.f, 0.f, 0.f};
  gemm64(W1f + ((size_t)rt << 18) + (wn << 15) + l * 8, Af, acc);
  __syncthreads();                           // all X1 reads done
  epi_relu(Xs, b1 + (size_t)rt * 512, acc, wm, wn, r, q);
  __syncthreads();                           // h visible

  // ========== phase 3: out = h @ W2[rt]^T + b2[rt] ==========
  {
    const int mtg = w >> 1, nt3 = w & 1;     // 128x32 = 16 frags, 1 per wave
    const u16* Ah = Xs + (mtg << 9) + l * 8;
    const u16* B2 = W2f + ((size_t)rt << 14) + (nt3 << 13) + l * 8;
    f32x4 o = (f32x4){0.f, 0.f, 0.f, 0.f};
#pragma unroll
    for (int kt = 0; kt < 16; ++kt) {
      const bf16x8 af = *(const bf16x8*)(Ah + kt * 4096);
      const bf16x8 bf = *(const bf16x8*)(B2 + kt * 512);
      o = __builtin_amdgcn_mfma_f32_16x16x32_bf16(bf, af, o, 0, 0, 0);
    }
    const int col = (nt3 << 4) + (q << 2);
    const float4 bb = *(const float4*)&b2[rt * 32 + col];
    const float4 res = { o.x + bb.x, o.y + bb.y, o.z + bb.z, o.w + bb.w };
    *(float4*)&Out[(size_t)(b0 + (mtg << 4) + r) * 1024 + a * 32 + col] = res;
  }
}

// ---------------------------------------------------------------------------
extern "C" void kernel_launch(void* const* d_in, const int* in_sizes, int n_in,
                              void* d_out, int out_size, void* d_ws, size_t ws_size,
                              hipStream_t stream) {
  (void)in_sizes; (void)n_in; (void)out_size; (void)ws_size;
  const float* x0  = (const float*)d_in[0];
  const float* Wsh = (const float*)d_in[1];
  const float* bsh = (const float*)d_in[2];
  const float* W1  = (const float*)d_in[3];
  const float* b1  = (const float*)d_in[4];
  const float* W2  = (const float*)d_in[5];
  const float* b2  = (const float*)d_in[6];
  const int* route = (const int*)d_in[7];
  float* out = (float*)d_out;

  char* ws = (char*)d_ws;
  u16* Wsf = (u16*)(ws + 0);                      // 512*512*2    = 512 KB  frag-major
  u16* W1f = (u16*)(ws + 524288);                 // 32*512*512*2 = 16 MB   frag-major, source-indexed
  u16* W2f = (u16*)(ws + 524288 + 16777216);      // 32*32*512*2  = 1 MB    frag-major, source-indexed

  frag_cvt<<<dim3(4, 32, 1),  256, 0, stream>>>(Wsh, nullptr, Wsf, 512, 512);
  frag_cvt<<<dim3(4, 32, 32), 256, 0, stream>>>(W1, route, W1f, 512, 512);   // only used experts
  frag_cvt<<<dim3(4, 2, 32),  256, 0, stream>>>(W2, route, W2f, 512, 32);    // only used experts
  fused_mlp<<<dim3(1024), 1024, 0, stream>>>(x0, Wsf, bsh, W1f, b1, W2f, b2, route, out);
}

// Round 3
// 535.876 us; speedup vs baseline: 1.1449x; 1.1449x over previous
//
#include <hip/hip_runtime.h>
#include <cstdint>
#include <cstddef>

typedef __bf16 bf16x8 __attribute__((ext_vector_type(8)));
typedef float f32x4 __attribute__((ext_vector_type(4)));
typedef unsigned short u16;
typedef u16 u16x4 __attribute__((ext_vector_type(4)));
typedef u16 u16x8 __attribute__((ext_vector_type(8)));

// fp32 -> bf16 round-to-nearest-even
__device__ __forceinline__ u16 f2bf(float f) {
  union { float f; unsigned u; } v; v.f = f;
  return (u16)((v.u + 0x7FFFu + ((v.u >> 16) & 1u)) >> 16);
}

__device__ __forceinline__ void cvt_wr(u16* dst, float4 v) {
  const u16x4 d = { f2bf(v.x), f2bf(v.y), f2bf(v.z), f2bf(v.w) };
  *(u16x4*)dst = d;
}

// ---------------------------------------------------------------------------
// Pre-pass: fp32 -> bf16 + MFMA *fragment-major* layout, SOURCE-indexed.
// If sel != null: convert plane s only if s appears in sel[0..31] (route dedup).
// out[(((s*NB + nb)*KT + kt)*64 + l)*8 + e] = in[s][kt*32 + (l>>4)*8 + e][nb*16 + (l&15)]
// ---------------------------------------------------------------------------
__global__ void frag_cvt(const float* __restrict__ in, const int* __restrict__ sel,
                         u16* __restrict__ out, int K, int N) {
  const int s = blockIdx.z;
  if (sel) {
    bool need = false;
#pragma unroll
    for (int i = 0; i < 32; ++i) need |= (sel[i] == s);
    if (!need) return;
  }
  const int f = threadIdx.x >> 6, l = threadIdx.x & 63;
  const int r = l & 15, q = l >> 4;
  const int kt = blockIdx.x * 4 + f;
  const int nb = blockIdx.y;
  const int KT = K >> 5, NB = N >> 4;
  const float* ip = in + (size_t)s * K * N + (size_t)(kt * 32 + q * 8) * N + nb * 16 + r;
  u16x8 d;
#pragma unroll
  for (int e = 0; e < 8; ++e) d[e] = f2bf(ip[(size_t)e * N]);
  *(u16x8*)&out[((((size_t)s * NB + nb) * KT + kt) * 64 + l) * 8] = d;
}

// relu + bias epilogue -> frag-major Xs.
// lane (r,q) acc[mt][nt] holds X[mt*16+r][wn*32 + nt*16 + q*4 + j]; kt-slice = wn.
__device__ __forceinline__ void epi_relu(u16* __restrict__ Xs, const float* __restrict__ bias,
                                         f32x4 acc[8][2], int wn, int r, int q) {
#pragma unroll
  for (int mt = 0; mt < 8; ++mt) {
#pragma unroll
    for (int nt = 0; nt < 2; ++nt) {
      const int col = wn * 32 + nt * 16 + q * 4;
      const int q2 = (col >> 3) & 3;
      const float4 bb = *(const float4*)&bias[col];
      const f32x4 v = acc[mt][nt];
      const u16x4 d = { f2bf(fmaxf(v.x + bb.x, 0.f)), f2bf(fmaxf(v.y + bb.y, 0.f)),
                        f2bf(fmaxf(v.z + bb.z, 0.f)), f2bf(fmaxf(v.w + bb.w, 0.f)) };
      *(u16x4*)&Xs[((wn * 8 + mt) * 64 + q2 * 16 + r) * 8 + (q & 1) * 4] = d;
    }
  }
}

// ---------------------------------------------------------------------------
// Fused 3-layer MLP per (128-row batch tile, agent). 1024 threads / 16 waves.
// Xs: 128 KB frag-major [kt 16][MT 8][lane 64][e 8] (x0 -> X1 -> h in place).
// Wave wn (0..15): FULL M=128, n-slice 32 (acc[8][2]) -> B bytes per MFMA
// halved vs 64x64 waves: per CU per kt-step B = 32 KB (585 cyc L2) vs
// 256 MFMA (1242 cyc) = 2:1 margin.
// Phase 0 fused into phase-1 k-loop: slice kt+2 global loads early-issued
// (3-slot reg rotation), cvt+ds_write slice kt+1 after MFMA burst, 1 barrier/kt.
// Phase 2/3 barrier-free k-loops.
// ---------------------------------------------------------------------------
__global__ __launch_bounds__(1024, 4)
void fused_mlp(const float* __restrict__ X0, const u16* __restrict__ Wsf,
               const float* __restrict__ bsh, const u16* __restrict__ W1f,
               const float* __restrict__ b1, const u16* __restrict__ W2f,
               const float* __restrict__ b2, const int* __restrict__ route,
               float* __restrict__ Out) {
  __shared__ u16 Xs[65536];                  // 128 KB

  const int tid = threadIdx.x;
  const int w = tid >> 6, l = tid & 63;
  const int r = l & 15, q = l >> 4;
  const int wn = w;                          // n-slice of 32

  // XCD-pinned: agent a on xcd = a>>2 (distinct-expert set <= 2 MB per L2)
  const int bid = blockIdx.x;                // 1024 blocks, 1024 % 8 == 0
  const int xcd = bid & 7, idx = bid >> 3;   // idx 0..127 per xcd
  const int a = (xcd << 2) | (idx >> 5);
  const int b0 = (idx & 31) << 7;            // 128-row tile
  const int rt = route[a];

  // x0 staging map: thread -> (row sm, col-quad scq); per kt-slice one float4.
  const int sm = tid >> 3, scq = tid & 7;
  const float* gx = X0 + (((size_t)(b0 + sm) * 32 + a) << 9) + (scq << 2);
  const int sdst = (((sm >> 4) << 6) + ((scq >> 1) << 4) + (sm & 15)) * 8 + (scq & 1) * 4;

  const u16* Af = Xs + l * 8;                // A frag: + kt*4096 + mt*512
  const u16* Bw = Wsf + (wn << 14) + l * 8;  // nb = 2*wn + nt: nt stride 8192, kt stride 512

  f32x4 acc[8][2];
#pragma unroll
  for (int mt = 0; mt < 8; ++mt)
#pragma unroll
    for (int nt = 0; nt < 2; ++nt) acc[mt][nt] = (f32x4){0.f, 0.f, 0.f, 0.f};

  // ========== phase 1 (x0 conversion fused) ==========
  float4 vb0, vb1, vb2;                      // slice s lives in vb[s % 3]
  vb0 = *(const float4*)(gx);                // slice 0
  vb1 = *(const float4*)(gx + 32);           // slice 1
  cvt_wr(&Xs[sdst], vb0);                    // write slice 0
  __syncthreads();

  bf16x8 bc0 = *(const bf16x8*)(Bw);
  bf16x8 bc1 = *(const bf16x8*)(Bw + 8192);
#pragma unroll
  for (int kt = 0; kt < 16; ++kt) {
    // early-issue x0 slice kt+2 (slot (kt+2)%3, free since iter kt-2)
    if (kt + 2 < 16) {
      const float4 t = *(const float4*)(gx + (kt + 2) * 32);
      if ((kt + 2) % 3 == 0) vb0 = t; else if ((kt + 2) % 3 == 1) vb1 = t; else vb2 = t;
    }
    bf16x8 bn0, bn1;
    if (kt < 15) {
      bn0 = *(const bf16x8*)(Bw + (kt + 1) * 512);
      bn1 = *(const bf16x8*)(Bw + 8192 + (kt + 1) * 512);
    }
#pragma unroll
    for (int mt = 0; mt < 8; ++mt) {
      const bf16x8 af = *(const bf16x8*)(Af + kt * 4096 + mt * 512);
      acc[mt][0] = __builtin_amdgcn_mfma_f32_16x16x32_bf16(bc0, af, acc[mt][0], 0, 0, 0);
      acc[mt][1] = __builtin_amdgcn_mfma_f32_16x16x32_bf16(bc1, af, acc[mt][1], 0, 0, 0);
    }
    if (kt < 15) {                           // write slice kt+1, then sync
      const float4 s = ((kt + 1) % 3 == 0) ? vb0 : ((kt + 1) % 3 == 1) ? vb1 : vb2;
      cvt_wr(&Xs[(kt + 1) * 4096 + sdst], s);
      __syncthreads();
    }
    bc0 = bn0; bc1 = bn1;
  }
  __syncthreads();                           // all x0 reads done
  epi_relu(Xs, bsh, acc, wn, r, q);
  __syncthreads();                           // X1 visible

  // ========== phase 2: h = relu(X1 @ W1[rt]^T + b1[rt]) ==========
#pragma unroll
  for (int mt = 0; mt < 8; ++mt)
#pragma unroll
    for (int nt = 0; nt < 2; ++nt) acc[mt][nt] = (f32x4){0.f, 0.f, 0.f, 0.f};
  {
    const u16* B1 = W1f + ((size_t)rt << 18) + (wn << 14) + l * 8;
    bc0 = *(const bf16x8*)(B1);
    bc1 = *(const bf16x8*)(B1 + 8192);
#pragma unroll
    for (int kt = 0; kt < 16; ++kt) {
      bf16x8 bn0, bn1;
      if (kt < 15) {
        bn0 = *(const bf16x8*)(B1 + (kt + 1) * 512);
        bn1 = *(const bf16x8*)(B1 + 8192 + (kt + 1) * 512);
      }
#pragma unroll
      for (int mt = 0; mt < 8; ++mt) {
        const bf16x8 af = *(const bf16x8*)(Af + kt * 4096 + mt * 512);
        acc[mt][0] = __builtin_amdgcn_mfma_f32_16x16x32_bf16(bc0, af, acc[mt][0], 0, 0, 0);
        acc[mt][1] = __builtin_amdgcn_mfma_f32_16x16x32_bf16(bc1, af, acc[mt][1], 0, 0, 0);
      }
      bc0 = bn0; bc1 = bn1;
    }
  }
  __syncthreads();                           // all X1 reads done
  epi_relu(Xs, b1 + (size_t)rt * 512, acc, wn, r, q);
  __syncthreads();                           // h visible

  // ========== phase 3: out = h @ W2[rt]^T + b2[rt] ==========
  {
    const int mtg = w >> 1, nt3 = w & 1;     // 128x32 out = 16 frags, 1 per wave
    const u16* Ah = Xs + (mtg << 9) + l * 8;
    const u16* B2 = W2f + ((size_t)rt << 14) + (nt3 << 13) + l * 8;
    f32x4 o = (f32x4){0.f, 0.f, 0.f, 0.f};
#pragma unroll
    for (int kt = 0; kt < 16; ++kt) {
      const bf16x8 af = *(const bf16x8*)(Ah + kt * 4096);
      const bf16x8 bf = *(const bf16x8*)(B2 + kt * 512);
      o = __builtin_amdgcn_mfma_f32_16x16x32_bf16(bf, af, o, 0, 0, 0);
    }
    const int col = (nt3 << 4) + (q << 2);
    const float4 bb = *(const float4*)&b2[rt * 32 + col];
    const float4 res = { o.x + bb.x, o.y + bb.y, o.z + bb.z, o.w + bb.w };
    *(float4*)&Out[(size_t)(b0 + (mtg << 4) + r) * 1024 + a * 32 + col] = res;
  }
}

// ---------------------------------------------------------------------------
extern "C" void kernel_launch(void* const* d_in, const int* in_sizes, int n_in,
                              void* d_out, int out_size, void* d_ws, size_t ws_size,
                              hipStream_t stream) {
  (void)in_sizes; (void)n_in; (void)out_size; (void)ws_size;
  const float* x0  = (const float*)d_in[0];
  const float* Wsh = (const float*)d_in[1];
  const float* bsh = (const float*)d_in[2];
  const float* W1  = (const float*)d_in[3];
  const float* b1  = (const float*)d_in[4];
  const float* W2  = (const float*)d_in[5];
  const float* b2  = (const float*)d_in[6];
  const int* route = (const int*)d_in[7];
  float* out = (float*)d_out;

  char* ws = (char*)d_ws;
  u16* Wsf = (u16*)(ws + 0);                      // 512*512*2    = 512 KB  frag-major
  u16* W1f = (u16*)(ws + 524288);                 // 32*512*512*2 = 16 MB   frag-major, source-indexed
  u16* W2f = (u16*)(ws + 524288 + 16777216);      // 32*32*512*2  = 1 MB    frag-major, source-indexed

  frag_cvt<<<dim3(4, 32, 1),  256, 0, stream>>>(Wsh, nullptr, Wsf, 512, 512);
  frag_cvt<<<dim3(4, 32, 32), 256, 0, stream>>>(W1, route, W1f, 512, 512);   // only used experts
  frag_cvt<<<dim3(4, 2, 32),  256, 0, stream>>>(W2, route, W2f, 512, 32);    // only used experts
  fused_mlp<<<dim3(1024), 1024, 0, stream>>>(x0, Wsf, bsh, W1f, b1, W2f, b2, route, out);
}